// Round 1
// baseline (1550.756 us; speedup 1.0000x reference)
//
#include <hip/hip_runtime.h>
#include <hip/hip_bf16.h>
#include <stdint.h>
#include <math.h>

#define T_TOK 4096
#define HD    1024
#define NE    16
#define FF    2816
#define TOPK  8
#define NPAIR (T_TOK*TOPK)

typedef __attribute__((ext_vector_type(8))) __bf16 bf16x8;
typedef __attribute__((ext_vector_type(4))) float  f32x4;

__device__ __forceinline__ unsigned short f2bf(float x){
  union { float f; unsigned u; } c; c.f = x;
  unsigned r = (c.u + 0x7FFFu + ((c.u >> 16) & 1u)) >> 16;
  return (unsigned short)r;
}
__device__ __forceinline__ float bf2f(unsigned short h){
  union { unsigned u; float f; } c; c.u = ((unsigned)h) << 16; return c.f;
}

// async global->LDS, 16B per lane; lds_dst must be the wave-uniform base.
__device__ __forceinline__ void gload16(const void* src, void* lds_dst){
  __builtin_amdgcn_global_load_lds((const __attribute__((address_space(1))) unsigned int*)src,
                                   (__attribute__((address_space(3))) unsigned int*)lds_dst,
                                   16, 0, 0);
}

// ---------------- fp32 -> bf16 (RNE) conversion ----------------
__global__ __launch_bounds__(256) void convert_bf16_kernel(
    const float* __restrict__ src, unsigned short* __restrict__ dst, int n4)
{
  int i = blockIdx.x * blockDim.x + threadIdx.x;
  int stride = gridDim.x * blockDim.x;
  for (; i < n4; i += stride){
    float4 v = ((const float4*)src)[i];
    ushort4 o;
    o.x = f2bf(v.x); o.y = f2bf(v.y); o.z = f2bf(v.z); o.w = f2bf(v.w);
    ((ushort4*)dst)[i] = o;
  }
}

// ---------------- router: logits (fp32), top-8, softmax; also x->bf16 ----------------
__global__ __launch_bounds__(256) void router_kernel(
    const float* __restrict__ x, const float* __restrict__ rw,
    unsigned short* __restrict__ xbf, int* __restrict__ topk_idx, float* __restrict__ topk_w)
{
  __shared__ float xs[HD];
  __shared__ float lg[NE];
  const int t   = blockIdx.x;
  const int tid = threadIdx.x;
  const int lane = tid & 63;
  const int wid  = tid >> 6;

  float4 v = ((const float4*)(x + (size_t)t*HD))[tid];
  ((float4*)xs)[tid] = v;
  ushort4 o;
  o.x = f2bf(v.x); o.y = f2bf(v.y); o.z = f2bf(v.z); o.w = f2bf(v.w);
  ((ushort4*)(xbf + (size_t)t*HD))[tid] = o;
  __syncthreads();

  for (int ee = 0; ee < 4; ++ee){
    int e = wid*4 + ee;
    const float* w = rw + (size_t)e*HD;
    float p = 0.f;
    for (int j = lane; j < HD; j += 64) p += xs[j] * w[j];
    #pragma unroll
    for (int offs = 32; offs; offs >>= 1) p += __shfl_xor(p, offs, 64);
    if (lane == 0) lg[e] = p;
  }
  __syncthreads();

  if (tid == 0){
    float vals[NE];
    #pragma unroll
    for (int e = 0; e < NE; ++e) vals[e] = lg[e];
    int   idx[TOPK]; float tv[TOPK];
    for (int k = 0; k < TOPK; ++k){
      int bi = 0; float bv = -3.4e38f;
      for (int e = 0; e < NE; ++e) if (vals[e] > bv){ bv = vals[e]; bi = e; }
      idx[k] = bi; tv[k] = bv; vals[bi] = -3.4e38f;
    }
    float m = tv[0];
    float ex[TOPK]; float s = 0.f;
    for (int k = 0; k < TOPK; ++k){ ex[k] = expf(tv[k] - m); s += ex[k]; }
    float inv = 1.f / s;
    for (int k = 0; k < TOPK; ++k){
      topk_idx[t*TOPK + k] = idx[k];
      topk_w [t*TOPK + k] = ex[k] * inv;
    }
  }
}

// ---------------- per-expert counts ----------------
__global__ __launch_bounds__(256) void count_kernel(
    const int* __restrict__ topk_idx, int* __restrict__ cnt)
{
  const int e = blockIdx.x;
  const int tid = threadIdx.x;
  __shared__ int wc[4];
  int c = 0;
  for (int t = tid; t < T_TOK; t += 256){
    bool f = false;
    #pragma unroll
    for (int k = 0; k < TOPK; ++k) f |= (topk_idx[t*TOPK + k] == e);
    c += f ? 1 : 0;
  }
  #pragma unroll
  for (int offs = 32; offs; offs >>= 1) c += __shfl_xor(c, offs, 64);
  if ((tid & 63) == 0) wc[tid >> 6] = c;
  __syncthreads();
  if (tid == 0) cnt[e] = wc[0] + wc[1] + wc[2] + wc[3];
}

// ---------------- deterministic compacted token lists per expert ----------------
__global__ __launch_bounds__(256) void lists_kernel(
    const int* __restrict__ topk_idx, const int* __restrict__ cnt,
    int* __restrict__ rows, int* __restrict__ slot_of, int* __restrict__ offs_out)
{
  const int e = blockIdx.x;
  const int tid = threadIdx.x;
  const int lane = tid & 63;
  const int wid  = tid >> 6;
  int off = 0;
  for (int i = 0; i < e; ++i) off += cnt[i];
  if (tid == 0) offs_out[e] = off;

  __shared__ int wc[4];
  int base = 0;
  for (int c0 = 0; c0 < T_TOK; c0 += 256){
    int t = c0 + tid;
    int kpos = -1;
    #pragma unroll
    for (int k = 0; k < TOPK; ++k) if (topk_idx[t*TOPK + k] == e) kpos = k;
    bool f = (kpos >= 0);
    unsigned long long m = __ballot(f);
    if (lane == 0) wc[wid] = __popcll(m);
    __syncthreads();
    int p = base;
    for (int w = 0; w < wid; ++w) p += wc[w];
    p += __popcll(m & ((1ULL << lane) - 1ULL));
    if (f){
      rows[off + p] = t;
      slot_of[t*TOPK + kpos] = off + p;
    }
    int tot = wc[0] + wc[1] + wc[2] + wc[3];
    __syncthreads();
    base += tot;
  }
}

// ---------------- stage-1: h = silu(x@gateT) * (x@upT), grouped by expert ----------------
// tile 128(M tokens) x 64(F), BK=32, 4 waves (2x2), wave tile 64x32
__global__ __launch_bounds__(256) void gemm_gateup(
    const unsigned short* __restrict__ xbf,   // [T][HD] bf16
    const unsigned short* __restrict__ gw,    // [NE][FF][HD] bf16
    const unsigned short* __restrict__ uw,    // [NE][FF][HD] bf16
    const int* __restrict__ rows, const int* __restrict__ cnt, const int* __restrict__ offs,
    unsigned short* __restrict__ hbuf)        // [NPAIR][FF] bf16
{
  const int e  = blockIdx.z;
  const int c  = cnt[e];
  const int m0 = blockIdx.x * 128;
  if (m0 >= c) return;
  const int n0 = blockIdx.y * 64;
  const int off_e = offs[e];

  __shared__ unsigned short As[128*32];
  __shared__ unsigned short Bg[64*32];
  __shared__ unsigned short Bu[64*32];

  const int tid  = threadIdx.x;
  const int lane = tid & 63;
  const int wid  = tid >> 6;

  // A staging: 2 chunks of 16B per thread; chunk ci = j*256+tid -> row ci>>2, quad ci&3
  const unsigned short* a_src0;
  const unsigned short* a_src1;
  {
    int ci0 = tid;        int r0 = m0 + (ci0 >> 2); if (r0 > c-1) r0 = c-1;
    int ci1 = 256 + tid;  int r1 = m0 + (ci1 >> 2); if (r1 > c-1) r1 = c-1;
    int tok0 = rows[off_e + r0];
    int tok1 = rows[off_e + r1];
    a_src0 = xbf + (size_t)tok0*HD + (ci0 & 3)*8;
    a_src1 = xbf + (size_t)tok1*HD + (ci1 & 3)*8;
  }
  unsigned short* a_dst0 = &As[wid*512];
  unsigned short* a_dst1 = &As[2048 + wid*512];

  const int brow = n0 + (tid >> 2);
  const unsigned short* bg_src = gw + ((size_t)e*FF + brow)*HD + (tid & 3)*8;
  const unsigned short* bu_src = uw + ((size_t)e*FF + brow)*HD + (tid & 3)*8;
  unsigned short* bg_dst = &Bg[wid*512];
  unsigned short* bu_dst = &Bu[wid*512];

  const int ar = lane & 15;
  const int kb = lane >> 4;
  const int wm = wid >> 1;   // 0..1 (M)
  const int wn = wid & 1;    // 0..1 (N)

  f32x4 accg[4][2] = {};
  f32x4 accu[4][2] = {};

  for (int ks = 0; ks < HD/32; ++ks){
    __syncthreads();
    gload16(a_src0, a_dst0);
    gload16(a_src1, a_dst1);
    gload16(bg_src, bg_dst);
    gload16(bu_src, bu_dst);
    a_src0 += 32; a_src1 += 32; bg_src += 32; bu_src += 32;
    asm volatile("s_waitcnt vmcnt(0)" ::: "memory");
    __syncthreads();

    bf16x8 a[4];
    #pragma unroll
    for (int m = 0; m < 4; ++m)
      a[m] = *(const bf16x8*)&As[(wm*64 + m*16 + ar)*32 + kb*8];
    bf16x8 fg[2], fu[2];
    #pragma unroll
    for (int n = 0; n < 2; ++n){
      int r = (wn*32 + n*16 + ar)*32 + kb*8;
      fg[n] = *(const bf16x8*)&Bg[r];
      fu[n] = *(const bf16x8*)&Bu[r];
    }
    #pragma unroll
    for (int m = 0; m < 4; ++m){
      #pragma unroll
      for (int n = 0; n < 2; ++n){
        accg[m][n] = __builtin_amdgcn_mfma_f32_16x16x32_bf16(a[m], fg[n], accg[m][n], 0, 0, 0);
        accu[m][n] = __builtin_amdgcn_mfma_f32_16x16x32_bf16(a[m], fu[n], accu[m][n], 0, 0, 0);
      }
    }
  }

  // epilogue: silu(g)*u -> bf16
  #pragma unroll
  for (int m = 0; m < 4; ++m){
    #pragma unroll
    for (int n = 0; n < 2; ++n){
      int fcol = n0 + wn*32 + n*16 + ar;
      #pragma unroll
      for (int i = 0; i < 4; ++i){
        int r  = wm*64 + m*16 + kb*4 + i;
        int gr = m0 + r;
        if (gr < c){
          float g = accg[m][n][i];
          float u = accu[m][n][i];
          float s = g / (1.0f + expf(-g));
          hbuf[(size_t)(off_e + gr)*FF + fcol] = f2bf(s * u);
        }
      }
    }
  }
}

// ---------------- stage-2: y = h @ downT, grouped by expert ----------------
// tile 128(M slots) x 128(N=H), BK=32, 4 waves (2x2), wave tile 64x64
__global__ __launch_bounds__(256) void gemm_down(
    const unsigned short* __restrict__ hbuf,  // [NPAIR][FF] bf16
    const unsigned short* __restrict__ dw,    // [NE][HD][FF] bf16
    const int* __restrict__ cnt, const int* __restrict__ offs,
    unsigned short* __restrict__ ybuf)        // [NPAIR][HD] bf16
{
  const int e  = blockIdx.z;
  const int c  = cnt[e];
  const int m0 = blockIdx.x * 128;
  if (m0 >= c) return;
  const int n0 = blockIdx.y * 128;
  const int off_e = offs[e];

  __shared__ unsigned short As[128*32];
  __shared__ unsigned short Bs[128*32];

  const int tid  = threadIdx.x;
  const int lane = tid & 63;
  const int wid  = tid >> 6;

  const unsigned short* a_src0;
  const unsigned short* a_src1;
  {
    int ci0 = tid;        int r0 = m0 + (ci0 >> 2); if (r0 > c-1) r0 = c-1;
    int ci1 = 256 + tid;  int r1 = m0 + (ci1 >> 2); if (r1 > c-1) r1 = c-1;
    a_src0 = hbuf + (size_t)(off_e + r0)*FF + (ci0 & 3)*8;
    a_src1 = hbuf + (size_t)(off_e + r1)*FF + (ci1 & 3)*8;
  }
  unsigned short* a_dst0 = &As[wid*512];
  unsigned short* a_dst1 = &As[2048 + wid*512];

  const unsigned short* b_src0;
  const unsigned short* b_src1;
  {
    int ci0 = tid;       int r0 = n0 + (ci0 >> 2);
    int ci1 = 256 + tid; int r1 = n0 + (ci1 >> 2);
    b_src0 = dw + ((size_t)e*HD + r0)*FF + (ci0 & 3)*8;
    b_src1 = dw + ((size_t)e*HD + r1)*FF + (ci1 & 3)*8;
  }
  unsigned short* b_dst0 = &Bs[wid*512];
  unsigned short* b_dst1 = &Bs[2048 + wid*512];

  const int ar = lane & 15;
  const int kb = lane >> 4;
  const int wm = wid >> 1;
  const int wn = wid & 1;

  f32x4 acc[4][4] = {};

  for (int ks = 0; ks < FF/32; ++ks){
    __syncthreads();
    gload16(a_src0, a_dst0);
    gload16(a_src1, a_dst1);
    gload16(b_src0, b_dst0);
    gload16(b_src1, b_dst1);
    a_src0 += 32; a_src1 += 32; b_src0 += 32; b_src1 += 32;
    asm volatile("s_waitcnt vmcnt(0)" ::: "memory");
    __syncthreads();

    bf16x8 a[4], b[4];
    #pragma unroll
    for (int m = 0; m < 4; ++m)
      a[m] = *(const bf16x8*)&As[(wm*64 + m*16 + ar)*32 + kb*8];
    #pragma unroll
    for (int n = 0; n < 4; ++n)
      b[n] = *(const bf16x8*)&Bs[(wn*64 + n*16 + ar)*32 + kb*8];
    #pragma unroll
    for (int m = 0; m < 4; ++m){
      #pragma unroll
      for (int n = 0; n < 4; ++n){
        acc[m][n] = __builtin_amdgcn_mfma_f32_16x16x32_bf16(a[m], b[n], acc[m][n], 0, 0, 0);
      }
    }
  }

  #pragma unroll
  for (int m = 0; m < 4; ++m){
    #pragma unroll
    for (int n = 0; n < 4; ++n){
      int ycol = n0 + wn*64 + n*16 + ar;
      #pragma unroll
      for (int i = 0; i < 4; ++i){
        int r  = wm*64 + m*16 + kb*4 + i;
        int gr = m0 + r;
        if (gr < c){
          ybuf[(size_t)(off_e + gr)*HD + ycol] = f2bf(acc[m][n][i]);
        }
      }
    }
  }
}

// ---------------- combine: out[t] = sum_k w_k * y[slot_of[t,k]] ----------------
__global__ __launch_bounds__(256) void combine_kernel(
    const unsigned short* __restrict__ ybuf,
    const int* __restrict__ slot_of, const float* __restrict__ topk_w,
    float* __restrict__ out)
{
  const int t   = blockIdx.x;
  const int tid = threadIdx.x;
  const int c0  = tid * 4;
  float4 acc = {0.f, 0.f, 0.f, 0.f};
  #pragma unroll
  for (int k = 0; k < TOPK; ++k){
    int slot = slot_of[t*TOPK + k];
    float w  = topk_w[t*TOPK + k];
    ushort4 v = *(const ushort4*)&ybuf[(size_t)slot*HD + c0];
    acc.x += w * bf2f(v.x);
    acc.y += w * bf2f(v.y);
    acc.z += w * bf2f(v.z);
    acc.w += w * bf2f(v.w);
  }
  ((float4*)out)[(size_t)t*(HD/4) + tid] = acc;
}

extern "C" void kernel_launch(void* const* d_in, const int* in_sizes, int n_in,
                              void* d_out, int out_size, void* d_ws, size_t ws_size,
                              hipStream_t stream)
{
  const float* x  = (const float*)d_in[0];
  const float* rw = (const float*)d_in[1];
  const float* gw = (const float*)d_in[2];
  const float* uw = (const float*)d_in[3];
  const float* dw = (const float*)d_in[4];
  float* out = (float*)d_out;

  char* ws = (char*)d_ws;
  size_t off = 0;
  auto alloc = [&](size_t b) -> void* {
    void* p = ws + off;
    off += (b + 255) & ~(size_t)255;
    return p;
  };

  unsigned short* gwb  = (unsigned short*)alloc((size_t)NE*FF*HD*2);
  unsigned short* uwb  = (unsigned short*)alloc((size_t)NE*FF*HD*2);
  unsigned short* dwb  = (unsigned short*)alloc((size_t)NE*HD*FF*2);
  unsigned short* xbf  = (unsigned short*)alloc((size_t)T_TOK*HD*2);
  unsigned short* hbuf = (unsigned short*)alloc((size_t)NPAIR*FF*2);
  unsigned short* ybuf = (unsigned short*)alloc((size_t)NPAIR*HD*2);
  int*   tki   = (int*)alloc((size_t)T_TOK*TOPK*4);
  float* tkw   = (float*)alloc((size_t)T_TOK*TOPK*4);
  int*   rowsb = (int*)alloc((size_t)NPAIR*4);
  int*   slotf = (int*)alloc((size_t)NPAIR*4);
  int*   cntb  = (int*)alloc(NE*4);
  int*   offsb = (int*)alloc(NE*4);

  const int n4 = NE*FF*HD/4;
  convert_bf16_kernel<<<4096, 256, 0, stream>>>(gw, gwb, n4);
  convert_bf16_kernel<<<4096, 256, 0, stream>>>(uw, uwb, n4);
  convert_bf16_kernel<<<4096, 256, 0, stream>>>(dw, dwb, n4);

  router_kernel<<<T_TOK, 256, 0, stream>>>(x, rw, xbf, tki, tkw);
  count_kernel<<<NE, 256, 0, stream>>>(tki, cntb);
  lists_kernel<<<NE, 256, 0, stream>>>(tki, cntb, rowsb, slotf, offsb);

  gemm_gateup<<<dim3(32, FF/64, NE), 256, 0, stream>>>(xbf, gwb, uwb, rowsb, cntb, offsb, hbuf);
  gemm_down<<<dim3(32, HD/128, NE), 256, 0, stream>>>(hbuf, dwb, cntb, offsb, ybuf);
  combine_kernel<<<T_TOK, 256, 0, stream>>>(ybuf, slotf, tkw, out);
}